// Round 14
// baseline (975.737 us; speedup 1.0000x reference)
//
#include <hip/hip_runtime.h>
#include <hip/hip_bf16.h>
#include <math.h>

#define NROW   8192      // B*H*W z-rows
#define KCODE  8192      // codebook entries
#define CD     256
#define HWSZ   1024
#define NBLK   64        // 128-code blocks (R5/R10-proven pK layout)
#define MARGIN 7.5e-5f

#define QOFF   ((size_t)NROW * CD)   // 2097152: loss at QOFF, indices at QOFF+1

typedef __attribute__((ext_vector_type(8)))  short short8;
typedef __attribute__((ext_vector_type(4)))  float f32x4;
typedef __attribute__((ext_vector_type(16))) float f32x16;
typedef unsigned long long u64;

#define XST 132   // LDS row stride (floats) for xs/es [k][...]

// sortable key: high32 = monotone float map, low32 = code (lex tie -> low index)
__device__ __forceinline__ u64 makeKey(float v, int code) {
  unsigned u = __float_as_uint(v);
  unsigned m = (u & 0x80000000u) ? ~u : (u | 0x80000000u);
  return ((u64)m << 32) | (unsigned)code;
}
__device__ __forceinline__ float keyVal(u64 k) {
  unsigned m = (unsigned)(k >> 32);
  unsigned u = (m & 0x80000000u) ? (m ^ 0x80000000u) : ~m;
  return __uint_as_float(u);
}
__device__ __forceinline__ void ins3(u64 k, u64& t1, u64& t2, u64& t3) {
  if (k < t1) { t3 = t2; t2 = t1; t1 = k; }
  else if (k < t2) { t3 = t2; t2 = k; }
  else if (k < t3) { t3 = k; }
}

// ---------------- k1: exact-numpy x2 per row (R2/R9-proven) ----------------
__global__ __launch_bounds__(256) void x2_kernel(
    const float* __restrict__ z, float* __restrict__ x2g) {
  __shared__ float xs[32 * 260];
  int tid = threadIdx.x;
  int n0 = blockIdx.x * 32;
  int b = n0 >> 10;
  int hw0 = n0 & 1023;
  const float* zb = z + (size_t)b * (CD * HWSZ) + hw0;
  {
    int r = tid & 31;
    int cbase = tid >> 5;
    for (int it = 0; it < 32; ++it) {
      int c = cbase + it * 8;
      xs[r * 260 + c] = zb[(size_t)c * HWSZ + r];
    }
  }
  __syncthreads();
  if (tid < 32) {
#pragma clang fp contract(off)
    const float* xr = &xs[tid * 260];
    float r0[8], r1[8];
#pragma unroll
    for (int j = 0; j < 8; ++j) {
      float v = xr[j];       r0[j] = v * v;
      float w = xr[128 + j]; r1[j] = w * w;
    }
    for (int i = 8; i < 128; i += 8) {
#pragma unroll
      for (int j = 0; j < 8; ++j) {
        float v = xr[i + j];       float a  = v * v; r0[j] = r0[j] + a;
        float w = xr[128 + i + j]; float b2 = w * w; r1[j] = r1[j] + b2;
      }
    }
    float lo = ((r0[0] + r0[1]) + (r0[2] + r0[3])) + ((r0[4] + r0[5]) + (r0[6] + r0[7]));
    float hi = ((r1[0] + r1[1]) + (r1[2] + r1[3])) + ((r1[4] + r1[5]) + (r1[6] + r1[7]));
    x2g[n0 + tid] = lo + hi;
  }
}

// ---------------- k2: fp32 VALU GEMM (R2-pipe-model, spill-safe) + top-3 ------------
// NO MFMA (R5-R13 law: this box runs mfma_16x16x32_bf16 at ~586 cy/instr).
// Tile 128 codes x 128 rows; thread (cg=tid&15, rg=tid>>4) owns 8 codes x 8 rows.
// acc=64 VGPR, peak ~130 (R9 spilled at ~200 with acc[128]+staging[48]).
// LDS: xs[k][row] & es[k][code], stride 132 floats, 33 KB -> 4 blocks/CU.
__global__ __launch_bounds__(256, 2) void gemm_valu_top3_kernel(
    const float* __restrict__ z, const float* __restrict__ emb,
    u64* __restrict__ pK1, u64* __restrict__ pK2, u64* __restrict__ pK3) {
  __shared__ float xs[32 * XST];   // 16896 B
  __shared__ float es[32 * XST];   // 16896 B
  int tid = threadIdx.x;
  int bid = blockIdx.x;                     // 0..4095
  int swz = (bid & 7) * 512 + (bid >> 3);   // XCD swizzle (bijective, 4096%8==0)
  int cbx = swz & 63, rby = swz >> 6;
  int cb0 = cbx * 128;
  int rb0 = rby * 128;
  int cg = tid & 15;     // codes cb0 + cg*8 .. +7
  int rg = tid >> 4;     // rows  rb0 + rg*8 .. +7

  int b = rb0 >> 10;
  int hw0 = rb0 & 1023;
  const float* zb = z + (size_t)b * (CD * HWSZ) + hw0;

  float acc[64];
#pragma unroll
  for (int i = 0; i < 64; ++i) acc[i] = 0.f;

  // staging addresses
  int xc = tid >> 3;            // c_local 0..31
  int xh = (tid & 7) * 16;      // hw offset
  int ec = tid >> 1;            // code 0..127
  int ek = (tid & 1) * 16;      // k half

  for (int kc = 0; kc < 8; ++kc) {
    // global loads first (latency overlaps other waves)
    float4 xv0, xv1, xv2, xv3, ev0, ev1, ev2, ev3;
    {
      const float* src = zb + (size_t)(kc * 32 + xc) * HWSZ + xh;
      xv0 = *(const float4*)(src);
      xv1 = *(const float4*)(src + 4);
      xv2 = *(const float4*)(src + 8);
      xv3 = *(const float4*)(src + 12);
    }
    {
      const float* src = emb + (size_t)(cb0 + ec) * CD + kc * 32 + ek;
      ev0 = *(const float4*)(src);
      ev1 = *(const float4*)(src + 4);
      ev2 = *(const float4*)(src + 8);
      ev3 = *(const float4*)(src + 12);
    }
    __syncthreads();   // previous chunk's reads complete
    {
      float* xw = &xs[xc * XST + xh];
      *(float4*)(xw)      = xv0;
      *(float4*)(xw + 4)  = xv1;
      *(float4*)(xw + 8)  = xv2;
      *(float4*)(xw + 12) = xv3;
    }
    { // transpose-write e: es[k][code]
      float* eb = &es[ek * XST + ec];
      eb[0]        = ev0.x; eb[XST]      = ev0.y; eb[2 * XST]  = ev0.z; eb[3 * XST]  = ev0.w;
      eb[4 * XST]  = ev1.x; eb[5 * XST]  = ev1.y; eb[6 * XST]  = ev1.z; eb[7 * XST]  = ev1.w;
      eb[8 * XST]  = ev2.x; eb[9 * XST]  = ev2.y; eb[10 * XST] = ev2.z; eb[11 * XST] = ev2.w;
      eb[12 * XST] = ev3.x; eb[13 * XST] = ev3.y; eb[14 * XST] = ev3.z; eb[15 * XST] = ev3.w;
    }
    __syncthreads();   // tile ready

    for (int k = 0; k < 32; ++k) {
      float a8[8], b8[8];
      {
        const float* xr = &xs[k * XST + rg * 8];
        *(float4*)&a8[0] = *(const float4*)(xr);
        *(float4*)&a8[4] = *(const float4*)(xr + 4);
      }
      {
        const float* er = &es[k * XST + cg * 8];
        *(float4*)&b8[0] = *(const float4*)(er);
        *(float4*)&b8[4] = *(const float4*)(er + 4);
      }
#pragma unroll
      for (int ii = 0; ii < 8; ++ii)
#pragma unroll
        for (int jj = 0; jj < 8; ++jj)
          acc[ii * 8 + jj] = fmaf(a8[ii], b8[jj], acc[ii * 8 + jj]);
    }
  }

  // epilogue: per-row top-3 over 128 codes, fully in-wave (16-lane cg shfl merge).
  // v = -2*dot (x2 cancels per-row; monotone). Ascending code order -> first-occ.
#pragma unroll
  for (int ii = 0; ii < 8; ++ii) {
    u64 t1 = ~0ull, t2 = ~0ull, t3 = ~0ull;
#pragma unroll
    for (int jj = 0; jj < 8; ++jj) {
      float v = -2.0f * acc[ii * 8 + jj];
      ins3(makeKey(v, cb0 + cg * 8 + jj), t1, t2, t3);
    }
#pragma unroll
    for (int off = 1; off < 16; off <<= 1) {   // merge across the 16 cg lanes
      u64 o1 = __shfl_xor(t1, off, 64);
      u64 o2 = __shfl_xor(t2, off, 64);
      u64 o3 = __shfl_xor(t3, off, 64);
      ins3(o1, t1, t2, t3); ins3(o2, t1, t2, t3); ins3(o3, t1, t2, t3);
    }
    if (cg == 0) {
      size_t o = (size_t)cbx * NROW + rb0 + rg * 8 + ii;
      pK1[o] = t1; pK2[o] = t2; pK3[o] = t3;
    }
  }
}

// ---------------- k3: merge blocks + exact re-rank (R2 semantics, R10-validated) ------
__global__ __launch_bounds__(256) void merge_rerank_kernel(
    const float* __restrict__ z, const float* __restrict__ emb,
    const u64* __restrict__ pK1, const u64* __restrict__ pK2,
    const u64* __restrict__ pK3, const float* __restrict__ x2g,
    int* __restrict__ idx, float* __restrict__ out) {
  int n = blockIdx.x * 256 + threadIdx.x;
  u64 kmin = ~0ull;
  for (int blk = 0; blk < NBLK; ++blk) {
    u64 k = pK1[(size_t)blk * NROW + n];
    if (k < kmin) kmin = k;
  }
  float vcut = keyVal(kmin) + MARGIN;
  int cand[8]; int nc = 0;
  for (int blk = 0; blk < NBLK; ++blk) {
    size_t o = (size_t)blk * NROW + n;
    u64 k1 = pK1[o], k2 = pK2[o], k3 = pK3[o];
    if (keyVal(k1) <= vcut && nc < 8) cand[nc++] = (int)(k1 & 0xffffffffu);
    if (keyVal(k2) <= vcut && nc < 8) cand[nc++] = (int)(k2 & 0xffffffffu);
    if (keyVal(k3) <= vcut && nc < 8) cand[nc++] = (int)(k3 & 0xffffffffu);
  }
  int b = n >> 10, hw = n & 1023;
  const float* zp = z + (size_t)b * (CD * HWSZ) + hw;
  float x2 = x2g[n];
  float bs = INFINITY; int bi = 0x7fffffff;
  for (int c0 = 0; c0 < nc; ++c0) {
    int k = cand[c0];
    const float* ep = emb + (size_t)k * CD;
    float acc = 0.f;
    for (int c = 0; c < CD; ++c)                 // sequential fmaf chain == R2 dot
      acc = fmaf(zp[(size_t)c * HWSZ], ep[c], acc);
    float s = fmaf(-2.f, acc, x2);               // single rounding == np grid
    if (s < bs || (s == bs && k < bi)) { bs = s; bi = k; }
  }
  idx[n] = bi;
  out[QOFF + 1 + n] = (float)bi;
}

// ---------------- k4: gather quantized + loss partials (R2-proven) ----------------
__global__ __launch_bounds__(256) void gather_kernel(
    const float* __restrict__ z, const float* __restrict__ emb,
    const int* __restrict__ idx, float* __restrict__ out,
    float* __restrict__ lossPart) {
  __shared__ int sidx[64];
  __shared__ float swsum[4];
  int tid = threadIdx.x;
  int bid = blockIdx.x;
  int n0 = bid * 64;
  if (tid < 64) sidx[tid] = idx[n0 + tid];
  __syncthreads();
  int lane = tid & 63;
  int cw = tid >> 6;
  int b = n0 >> 10;
  int hw = (n0 & 1023) + lane;
  const float* erow = emb + (size_t)sidx[lane] * CD;
  float lacc = 0.f;
  for (int ci = 0; ci < 64; ++ci) {
    int c = cw * 64 + ci;
    float q = erow[c];
    size_t o = (size_t)b * (CD * HWSZ) + (size_t)c * HWSZ + hw;
    float zv = z[o];
    out[o] = q;
    float d = q - zv;
    lacc += d * d;
  }
#pragma unroll
  for (int off = 32; off > 0; off >>= 1) lacc += __shfl_down(lacc, off, 64);
  if (lane == 0) swsum[cw] = lacc;
  __syncthreads();
  if (tid == 0) lossPart[bid] = swsum[0] + swsum[1] + swsum[2] + swsum[3];
}

__global__ void loss_kernel(const float* __restrict__ lossPart, float* __restrict__ out) {
  if (threadIdx.x == 0) {
    double s = 0.0;
    for (int i = 0; i < 128; ++i) s += (double)lossPart[i];
    out[QOFF] = (float)(s * 1.25 / (double)(NROW * CD));
  }
}

// ================= PROBE: 32x32x16 bf16 MFMA throughput =================
// 4 independent accumulators x 1200 iters = 4800 MFMA/wave; 256 blocks x 64 thr
// (1 wave/CU). Healthy (<=50cy): ~30us, invisible in top-5. Broken (>=200cy):
// >=960us, floods top-5 -> R15 falls back to VALU permanently.
__global__ __launch_bounds__(64) void probe_mfma32_kernel() {
  int lane = threadIdx.x & 63;
  short8 a, b;
#pragma unroll
  for (int j = 0; j < 8; ++j) { a[j] = (short)(lane + j); b[j] = (short)(lane * 2 + j); }
  f32x16 c0 = {}, c1 = {}, c2 = {}, c3 = {};
  for (int it = 0; it < 1200; ++it) {
    c0 = __builtin_amdgcn_mfma_f32_32x32x16_bf16(a, b, c0, 0, 0, 0);
    c1 = __builtin_amdgcn_mfma_f32_32x32x16_bf16(a, b, c1, 0, 0, 0);
    c2 = __builtin_amdgcn_mfma_f32_32x32x16_bf16(a, b, c2, 0, 0, 0);
    c3 = __builtin_amdgcn_mfma_f32_32x32x16_bf16(a, b, c3, 0, 0, 0);
  }
  float s = c0[0] + c1[0] + c2[0] + c3[0];
  asm volatile("" :: "v"(s));
}

extern "C" void kernel_launch(void* const* d_in, const int* in_sizes, int n_in,
                              void* d_out, int out_size, void* d_ws, size_t ws_size,
                              hipStream_t stream) {
  const float* z   = (const float*)d_in[0];
  const float* emb = (const float*)d_in[1];
  float* out = (float*)d_out;

  // ws: pK1|pK2|pK3 (3 x 4MB) | x2 | idx | lossPart -> 12.07 MB (R5-proven size)
  u64* pK1 = (u64*)d_ws;
  u64* pK2 = pK1 + (size_t)NBLK * NROW;
  u64* pK3 = pK2 + (size_t)NBLK * NROW;
  float* x2g = (float*)(pK3 + (size_t)NBLK * NROW);
  int* idx = (int*)(x2g + NROW);
  float* lossPart = (float*)(idx + NROW);

  hipLaunchKernelGGL(x2_kernel, dim3(NROW / 32), dim3(256), 0, stream, z, x2g);
  hipLaunchKernelGGL(gemm_valu_top3_kernel, dim3((KCODE / 128) * (NROW / 128)), dim3(256),
                     0, stream, z, emb, pK1, pK2, pK3);
  hipLaunchKernelGGL(merge_rerank_kernel, dim3(NROW / 256), dim3(256), 0, stream,
                     z, emb, pK1, pK2, pK3, x2g, idx, out);
  hipLaunchKernelGGL(gather_kernel, dim3(NROW / 64), dim3(256), 0, stream,
                     z, emb, idx, out, lossPart);
  hipLaunchKernelGGL(loss_kernel, dim3(1), dim3(64), 0, stream, lossPart, out);
  hipLaunchKernelGGL(probe_mfma32_kernel, dim3(256), dim3(64), 0, stream);
}

// Round 15
// 486.989 us; speedup vs baseline: 2.0036x; 2.0036x over previous
//
#include <hip/hip_runtime.h>
#include <hip/hip_bf16.h>
#include <math.h>

#define NROW   8192      // B*H*W z-rows
#define KCODE  8192      // codebook entries
#define CD     256
#define HWSZ   1024
#define NBLK   32        // 256-code blocks (R11/R13-validated top-3 layout)
#define MARGIN 7.5e-5f

#define QOFF   ((size_t)NROW * CD)   // 2097152: loss at QOFF, indices at QOFF+1

typedef __attribute__((ext_vector_type(8)))  short short8;
typedef __attribute__((ext_vector_type(16))) float f32x16;
typedef unsigned long long u64;

#define LDSTB  136                    // LDS row stride bytes (34 dwords; 2-way reads)
#define TILEB  (256 * LDSTB)          // 34816 B per tile buffer

// sortable key: high32 = monotone float map, low32 = code (lex tie -> low index)
__device__ __forceinline__ u64 makeKey(float v, int code) {
  unsigned u = __float_as_uint(v);
  unsigned m = (u & 0x80000000u) ? ~u : (u | 0x80000000u);
  return ((u64)m << 32) | (unsigned)code;
}
__device__ __forceinline__ float keyVal(u64 k) {
  unsigned m = (unsigned)(k >> 32);
  unsigned u = (m & 0x80000000u) ? (m ^ 0x80000000u) : ~m;
  return __uint_as_float(u);
}
__device__ __forceinline__ void ins3(u64 k, u64& t1, u64& t2, u64& t3) {
  if (k < t1) { t3 = t2; t2 = t1; t1 = k; }
  else if (k < t2) { t3 = t2; t2 = k; }
  else if (k < t3) { t3 = k; }
}
__device__ __forceinline__ unsigned short f2bf(float f) {
  __hip_bfloat16 h = __float2bfloat16(f);
  return *(unsigned short*)&h;
}

// ---------------- k1: z -> Xhi bf16 [n][c] (d_ws) + exact-numpy x2 (R2-proven) ------
__global__ __launch_bounds__(256) void splitz_x2_kernel(
    const float* __restrict__ z, unsigned short* __restrict__ Xhi,
    float* __restrict__ x2g) {
  __shared__ float xs[32 * 260];
  int tid = threadIdx.x;
  int n0 = blockIdx.x * 32;
  int b = n0 >> 10;
  int hw0 = n0 & 1023;
  const float* zb = z + (size_t)b * (CD * HWSZ) + hw0;
  {
    int r = tid & 31;
    int cbase = tid >> 5;
    for (int it = 0; it < 32; ++it) {
      int c = cbase + it * 8;
      xs[r * 260 + c] = zb[(size_t)c * HWSZ + r];
    }
  }
  __syncthreads();
  if (tid < 32) {
#pragma clang fp contract(off)
    const float* xr = &xs[tid * 260];
    float r0[8], r1[8];
#pragma unroll
    for (int j = 0; j < 8; ++j) {
      float v = xr[j];       r0[j] = v * v;
      float w = xr[128 + j]; r1[j] = w * w;
    }
    for (int i = 8; i < 128; i += 8) {
#pragma unroll
      for (int j = 0; j < 8; ++j) {
        float v = xr[i + j];       float a  = v * v; r0[j] = r0[j] + a;
        float w = xr[128 + i + j]; float b2 = w * w; r1[j] = r1[j] + b2;
      }
    }
    float lo = ((r0[0] + r0[1]) + (r0[2] + r0[3])) + ((r0[4] + r0[5]) + (r0[6] + r0[7]));
    float hi = ((r1[0] + r1[1]) + (r1[2] + r1[3])) + ((r1[4] + r1[5]) + (r1[6] + r1[7]));
    x2g[n0 + tid] = lo + hi;
  }
  for (int r = 0; r < 32; ++r) {
    float v = xs[r * 260 + tid];
    Xhi[(size_t)(n0 + r) * CD + tid] = f2bf(v);
  }
}

// ---------------- k2: emb -> Ehi bf16 (d_ws) ----------------
__global__ __launch_bounds__(256) void splite_kernel(
    const float* __restrict__ emb, unsigned short* __restrict__ Ehi) {
  int n = blockIdx.x * 256 + threadIdx.x;
  Ehi[n] = f2bf(emb[n]);
}

// ---------------- k3: R13 structure, inner engine = mfma_32x32x16 (probe-healthy) ----
// R14 probe: 32x32x16 absent from top-5 => <470cy/instr (16x16x32 is ~586cy — the
// R5-R13 invariant). Same 256^2 tile, dbuf LDS staging; per wave 4x2 MFMAs of 32x32,
// acc = 8 x f32x16 = 128 AGPR, arch ~100 VGPR -> fits 256 cap at (512,2), no spill.
__global__ __launch_bounds__(512, 2) void gemm_top3_kernel(
    const unsigned short* __restrict__ Eg,   // A [8192][256] bf16 (d_ws)
    const unsigned short* __restrict__ Xg,   // B [8192][256] bf16 (d_ws)
    u64* __restrict__ pK1, u64* __restrict__ pK2, u64* __restrict__ pK3) {
  __shared__ __align__(16) char SM[4 * TILEB];   // As0|As1|Bs0|Bs1 = 139264 B
  int tid = threadIdx.x;
  int bid = blockIdx.x;                          // 0..1023
  int swz = (bid & 7) * 128 + (bid >> 3);        // XCD swizzle (bijective, 1024%8==0)
  int cbx = swz >> 5;              // 0..31 slow: per-XCD A strip = 512KB
  int rby = swz & 31;              // 0..31
  int cb0 = cbx * 256;
  int rb0 = rby * 256;
  int wid = tid >> 6, lane = tid & 63;
  int l31 = lane & 31, lhd = lane >> 5;          // 32x32 operand lane split
  int wr = wid & 1, wcc = wid >> 1;              // wave tile: codes 128*wr, rows 64*wcc

  f32x16 acc[4][2];
#pragma unroll
  for (int i = 0; i < 4; ++i)
#pragma unroll
    for (int j = 0; j < 2; ++j) acc[i][j] = (f32x16){};

  // staging addressing (R13-verbatim): thread t covers rows (t>>3)+64m, 16B chunk (t&7)
  int srow = tid >> 3;
  int scol = (tid & 7) * 16;
  const char* gA = (const char*)Eg + ((size_t)(cb0 + srow)) * 512 + scol;
  const char* gB = (const char*)Xg + ((size_t)(rb0 + srow)) * 512 + scol;

  short8 ra[4], rb[4];
#define LOADCH(kc) { _Pragma("unroll") for (int m = 0; m < 4; ++m) { \
    ra[m] = *(const short8*)(gA + (size_t)(64 * m) * 512 + (kc) * 128); \
    rb[m] = *(const short8*)(gB + (size_t)(64 * m) * 512 + (kc) * 128); } }
#define WRITECH(buf) { _Pragma("unroll") for (int m = 0; m < 4; ++m) { \
    *(short8*)(SM + (buf) * TILEB + (srow + 64 * m) * LDSTB + scol) = ra[m]; \
    *(short8*)(SM + (2 + (buf)) * TILEB + (srow + 64 * m) * LDSTB + scol) = rb[m]; } }

  LOADCH(0)
  WRITECH(0)
  __syncthreads();
  for (int kc = 0; kc < 4; ++kc) {
    int cur = kc & 1;
    if (kc < 3) LOADCH(kc + 1)        // issue next chunk's globals early (T14)
    const char* As = SM + cur * TILEB;
    const char* Bs = SM + (2 + cur) * TILEB;
#pragma unroll
    for (int ks = 0; ks < 4; ++ks) {  // K=16 per step, 64 per chunk
      // A lane: row = 128*wr + 32*i + l31, k-slice: ks*32B + lhd*16B
      short8 af[4], bf[2];
#pragma unroll
      for (int i = 0; i < 4; ++i)
        af[i] = *(const short8*)(As + (128 * wr + 32 * i + l31) * LDSTB + ks * 32 + lhd * 16);
#pragma unroll
      for (int j = 0; j < 2; ++j)
        bf[j] = *(const short8*)(Bs + (64 * wcc + 32 * j + l31) * LDSTB + ks * 32 + lhd * 16);
#pragma unroll
      for (int i = 0; i < 4; ++i)
#pragma unroll
        for (int j = 0; j < 2; ++j)
          acc[i][j] = __builtin_amdgcn_mfma_f32_32x32x16_bf16(af[i], bf[j], acc[i][j], 0, 0, 0);
    }
    if (kc < 3) {
      __syncthreads();                // buf[nxt]'s previous readers done
      WRITECH((kc + 1) & 1)
      __syncthreads();                // writes visible before next compute
    }
  }
  __syncthreads();                    // frag reads done; overlay redK

  // ---- epilogue: top-3 per zrow over wave's 128 codes ----
  // 32x32 C/D (m74/m101-verified): zrow(col) = 32*j + (lane&31),
  // code(row) = 128*wr + 32*i + (reg&3) + 8*(reg>>2) + 4*lhd.
  // Lanes l and l+32 hold the SAME zrow but DISJOINT code quartets (+4*lhd)
  // -> xor-32 merge combines disjoint lists, no duplicate keys.
  u64* redK = (u64*)SM;               // [8 waves][64 rows][3] = 12 KB
#pragma unroll
  for (int j = 0; j < 2; ++j) {
    u64 t1 = ~0ull, t2 = ~0ull, t3 = ~0ull;
#pragma unroll
    for (int i = 0; i < 4; ++i)
#pragma unroll
      for (int r = 0; r < 16; ++r) {
        float v = -2.0f * acc[i][j][r];   // x2 cancels per-row; monotone
        int code = cb0 + 128 * wr + 32 * i + (r & 3) + 8 * (r >> 2) + 4 * lhd;
        ins3(makeKey(v, code), t1, t2, t3);
      }
    {
      u64 o1 = __shfl_xor(t1, 32, 64);
      u64 o2 = __shfl_xor(t2, 32, 64);
      u64 o3 = __shfl_xor(t3, 32, 64);
      ins3(o1, t1, t2, t3); ins3(o2, t1, t2, t3); ins3(o3, t1, t2, t3);
    }
    if (lhd == 0) {
      int zl = 32 * j + l31;            // row within wave's 64
      redK[(wid * 64 + zl) * 3 + 0] = t1;
      redK[(wid * 64 + zl) * 3 + 1] = t2;
      redK[(wid * 64 + zl) * 3 + 2] = t3;
    }
  }
  __syncthreads();
  if (tid < 256) {                      // merge the two code-half waves per row
    int wcc2 = tid >> 6, rl = tid & 63;
    int w0 = 2 * wcc2, w1 = 2 * wcc2 + 1;
    u64 t1 = redK[(w0 * 64 + rl) * 3 + 0];
    u64 t2 = redK[(w0 * 64 + rl) * 3 + 1];
    u64 t3 = redK[(w0 * 64 + rl) * 3 + 2];
    ins3(redK[(w1 * 64 + rl) * 3 + 0], t1, t2, t3);
    ins3(redK[(w1 * 64 + rl) * 3 + 1], t1, t2, t3);
    ins3(redK[(w1 * 64 + rl) * 3 + 2], t1, t2, t3);
    size_t o = (size_t)cbx * NROW + rb0 + tid;
    pK1[o] = t1; pK2[o] = t2; pK3[o] = t3;
  }
#undef LOADCH
#undef WRITECH
}

// ---------------- k4: merge blocks + exact re-rank (R2 semantics, R13-validated) ------
__global__ __launch_bounds__(256) void merge_rerank_kernel(
    const float* __restrict__ z, const float* __restrict__ emb,
    const u64* __restrict__ pK1, const u64* __restrict__ pK2,
    const u64* __restrict__ pK3, const float* __restrict__ x2g,
    int* __restrict__ idx, float* __restrict__ out) {
  int n = blockIdx.x * 256 + threadIdx.x;
  u64 kmin = ~0ull;
  for (int blk = 0; blk < NBLK; ++blk) {
    u64 k = pK1[(size_t)blk * NROW + n];
    if (k < kmin) kmin = k;
  }
  float vcut = keyVal(kmin) + MARGIN;
  int cand[8]; int nc = 0;
  for (int blk = 0; blk < NBLK; ++blk) {
    size_t o = (size_t)blk * NROW + n;
    u64 k1 = pK1[o], k2 = pK2[o], k3 = pK3[o];
    if (keyVal(k1) <= vcut && nc < 8) cand[nc++] = (int)(k1 & 0xffffffffu);
    if (keyVal(k2) <= vcut && nc < 8) cand[nc++] = (int)(k2 & 0xffffffffu);
    if (keyVal(k3) <= vcut && nc < 8) cand[nc++] = (int)(k3 & 0xffffffffu);
  }
  int b = n >> 10, hw = n & 1023;
  const float* zp = z + (size_t)b * (CD * HWSZ) + hw;
  float x2 = x2g[n];
  float bs = INFINITY; int bi = 0x7fffffff;
  for (int c0 = 0; c0 < nc; ++c0) {
    int k = cand[c0];
    const float* ep = emb + (size_t)k * CD;
    float acc = 0.f;
    for (int c = 0; c < CD; ++c)                 // sequential fmaf chain == R2 dot
      acc = fmaf(zp[(size_t)c * HWSZ], ep[c], acc);
    float s = fmaf(-2.f, acc, x2);               // single rounding == np grid
    if (s < bs || (s == bs && k < bi)) { bs = s; bi = k; }
  }
  idx[n] = bi;
  out[QOFF + 1 + n] = (float)bi;
}

// ---------------- k5: gather quantized + loss partials (R2-proven) ----------------
__global__ __launch_bounds__(256) void gather_kernel(
    const float* __restrict__ z, const float* __restrict__ emb,
    const int* __restrict__ idx, float* __restrict__ out,
    float* __restrict__ lossPart) {
  __shared__ int sidx[64];
  __shared__ float swsum[4];
  int tid = threadIdx.x;
  int bid = blockIdx.x;
  int n0 = bid * 64;
  if (tid < 64) sidx[tid] = idx[n0 + tid];
  __syncthreads();
  int lane = tid & 63;
  int cw = tid >> 6;
  int b = n0 >> 10;
  int hw = (n0 & 1023) + lane;
  const float* erow = emb + (size_t)sidx[lane] * CD;
  float lacc = 0.f;
  for (int ci = 0; ci < 64; ++ci) {
    int c = cw * 64 + ci;
    float q = erow[c];
    size_t o = (size_t)b * (CD * HWSZ) + (size_t)c * HWSZ + hw;
    float zv = z[o];
    out[o] = q;
    float d = q - zv;
    lacc += d * d;
  }
#pragma unroll
  for (int off = 32; off > 0; off >>= 1) lacc += __shfl_down(lacc, off, 64);
  if (lane == 0) swsum[cw] = lacc;
  __syncthreads();
  if (tid == 0) lossPart[bid] = swsum[0] + swsum[1] + swsum[2] + swsum[3];
}

__global__ void loss_kernel(const float* __restrict__ lossPart, float* __restrict__ out) {
  if (threadIdx.x == 0) {
    double s = 0.0;
    for (int i = 0; i < 128; ++i) s += (double)lossPart[i];
    out[QOFF] = (float)(s * 1.25 / (double)(NROW * CD));
  }
}

extern "C" void kernel_launch(void* const* d_in, const int* in_sizes, int n_in,
                              void* d_out, int out_size, void* d_ws, size_t ws_size,
                              hipStream_t stream) {
  const float* z   = (const float*)d_in[0];
  const float* emb = (const float*)d_in[1];
  float* out = (float*)d_out;

  size_t pkBytes = (size_t)NBLK * NROW * 8;   // 2 MB each
  char* wp = (char*)d_ws;
  unsigned short* Ehi = (unsigned short*)wp;  wp += (size_t)KCODE * CD * 2;  // 4 MB
  unsigned short* Xhi = (unsigned short*)wp;  wp += (size_t)NROW * CD * 2;   // 4 MB
  u64* pK1 = (u64*)wp;                        wp += pkBytes;                 // 2 MB
  float* x2g = (float*)wp;                    wp += (size_t)NROW * 4;
  int* idx = (int*)wp;                        wp += (size_t)NROW * 4;
  float* lossPart = (float*)wp;               wp += 512;

  // pK2/pK3: ws if it fits (Tier A), else d_out's quantized region (Tier B —
  // merge runs before gather overwrites; indices at QOFF+1 disjoint; R12/R13-proven).
  u64 *pK2, *pK3;
  size_t used = (size_t)(wp - (char*)d_ws);
  if (ws_size >= used + 2 * pkBytes) {
    pK2 = (u64*)wp;
    pK3 = (u64*)(wp + pkBytes);
  } else {
    pK2 = (u64*)d_out;
    pK3 = (u64*)((char*)d_out + pkBytes);
  }

  hipLaunchKernelGGL(splitz_x2_kernel, dim3(NROW / 32), dim3(256), 0, stream, z, Xhi, x2g);
  hipLaunchKernelGGL(splite_kernel, dim3((KCODE * CD) / 256), dim3(256), 0, stream, emb, Ehi);
  hipLaunchKernelGGL(gemm_top3_kernel, dim3((KCODE / 256) * (NROW / 256)), dim3(512), 0, stream,
                     Ehi, Xhi, pK1, pK2, pK3);
  hipLaunchKernelGGL(merge_rerank_kernel, dim3(NROW / 256), dim3(256), 0, stream,
                     z, emb, pK1, pK2, pK3, x2g, idx, out);
  hipLaunchKernelGGL(gather_kernel, dim3(NROW / 64), dim3(256), 0, stream,
                     z, emb, idx, out, lossPart);
  hipLaunchKernelGGL(loss_kernel, dim3(1), dim3(64), 0, stream, lossPart, out);
}